// Round 2
// baseline (1431.971 us; speedup 1.0000x reference)
//
#include <hip/hip_runtime.h>
#include <hip/hip_cooperative_groups.h>
#include <math.h>

namespace cg = cooperative_groups;

#define DD 128
#define TPB 512
#define SMAX 2048
#define NBLK_MAX 512

__device__ __forceinline__ float sigmoidf(float x) { return 1.0f / (1.0f + expf(-x)); }

// ---------------------------------------------------------------------------
// Predecessor kernel: block j scans i<j for last step sharing a node.
// ---------------------------------------------------------------------------
__global__ __launch_bounds__(64) void pred_kernel(
    const int* __restrict__ heads, const int* __restrict__ tails, int S,
    int* __restrict__ ph, int* __restrict__ pt) {
  const int j = blockIdx.x;
  if (j >= S) return;
  const int myh = heads[j], myt = tails[j];
  const int lane = threadIdx.x;
  int mph = -1, mpt = -1;
#pragma unroll 4
  for (int i = lane; i < j; i += 64) {
    int a = heads[i], b = tails[i];
    if (a == myh || b == myh) mph = i;
    if (a == myt || b == myt) mpt = i;
  }
#pragma unroll
  for (int off = 32; off > 0; off >>= 1) {
    mph = max(mph, __shfl_down(mph, off));
    mpt = max(mpt, __shfl_down(mpt, off));
  }
  if (lane == 0) { ph[j] = mph; pt[j] = mpt; }
}

// ---------------------------------------------------------------------------
// Finalize: fixpoint level relaxation + bucket by level.
// ---------------------------------------------------------------------------
__global__ __launch_bounds__(1024) void finalize_kernel(
    int S, const int* __restrict__ phg, const int* __restrict__ ptg,
    int* __restrict__ order, int* __restrict__ level_off, int* __restrict__ n_levels) {
  __shared__ int lvl[SMAX], ph[SMAX], pt[SMAX], cnt[SMAX];
  __shared__ int changed, maxl;
  const int tid = threadIdx.x;

  for (int j = tid; j < S; j += 1024) { ph[j] = phg[j]; pt[j] = ptg[j]; lvl[j] = 1; }
  __syncthreads();

  for (int it = 0; it < S + 2; ++it) {
    if (tid == 0) changed = 0;
    __syncthreads();
    for (int j = tid; j < S; j += 1024) {
      int l = 1;
      int a = ph[j]; if (a >= 0) l = lvl[a] + 1;
      int b = pt[j]; if (b >= 0) { int lb = lvl[b] + 1; if (lb > l) l = lb; }
      if (l != lvl[j]) { lvl[j] = l; changed = 1; }
    }
    __syncthreads();
    if (!changed) break;
    __syncthreads();
  }

  if (tid == 0) maxl = 0;
  __syncthreads();
  for (int j = tid; j < S; j += 1024) atomicMax(&maxl, lvl[j]);
  __syncthreads();
  const int M = maxl;

  for (int l = tid; l < M; l += 1024) cnt[l] = 0;
  __syncthreads();
  for (int j = tid; j < S; j += 1024) atomicAdd(&cnt[lvl[j] - 1], 1);
  __syncthreads();
  if (tid == 0) {
    int run = 0;
    level_off[0] = 0;
    for (int l = 0; l < M; ++l) { run += cnt[l]; level_off[l + 1] = run; }
    n_levels[0] = M;
  }
  __syncthreads();

  for (int l = tid; l < M; l += 1024) cnt[l] = 0;
  __syncthreads();
  for (int j = tid; j < S; j += 1024) {
    int lv = lvl[j] - 1;
    int pos = level_off[lv] + atomicAdd(&cnt[lv], 1);
    order[pos] = j;
  }
}

// ---------------------------------------------------------------------------
// R7: level-batched GEMM restructure.
// Same-level steps are node-disjoint (proof: two steps sharing a node are
// chained by pred links => strictly increasing levels). So each level of M
// steps is a batch-M GEMM against shared weights. This fixes the measured
// bottleneck (VALUBusy 5.5%, 95% latency stall at 8-16 FMA per weight load):
//  - weights pre-transposed once into k4-tiled T[k/4][e][4] -> one float4
//    load feeds 64 FMAs (16 rows x 4 k) per thread
//  - A-rows are wave-uniform broadcast loads (1 txn, L1-hot), no LDS staging
//  - 3 phases per level separated by grid.sync:
//    PH1: EH/ET/CADJ GEMMs + copies (out, old-hidden snapshots)
//    PH2: Z GEMMs (16x512 tiles), gates fused via LDS Z-tile, scatter c/h/rt
//    PH3: combiner GEMMs, rep scatter (tail wins on h==t)
// ---------------------------------------------------------------------------
struct PParams {
  const int* heads; const int* tails; const float* times;
  float* node_rep; float* cell_head; float* hidden_head; float* cell_tail; float* hidden_tail;
  const float* beh; const float* bet; const float* bh; const float* bt;
  const float* bdh; const float* bdt;
  const float* Wsrc[12];   // Weh1,Weh2,Wet1,Wet2,Wdh,Wdt,Wc1,Wc2,Wxh,Whh,Wxt,Wht
  float* Wt[12];           // k4-tiled transposed copies
  float* EH; float* ET; float* CADJH; float* CADJT;
  float* HTHold; float* HHTold; float* HNH; float* HNT;
  float* out; float* rt;
  const int* order; const int* level_off; const int* n_levels;
  int S;
};

#define FMA4(j, a, w) \
  acc[j] += (a).x * (w).x + (a).y * (w).y + (a).z * (w).z + (a).w * (w).w

__global__ __launch_bounds__(TPB, 1) void process_kernel(PParams p) {
  cg::grid_group grid = cg::this_grid();
  const int tid = threadIdx.x;
  const int bid = (int)blockIdx.x;
  const int nb  = (int)gridDim.x;

  __shared__ float Z[16 * 512];            // 32 KB, PH2 z-tile
  __shared__ int hL[64], tL[64], sL[64];
  __shared__ float decL[64];

  // ---- Phase 0: transpose weights into k4-tiled layout T[(k4*E+e)*4 + j]
  {
    const long total = 8L * 4096 + 4L * 16384;   // in float4 units
    for (long i = (long)bid * TPB + tid; i < total; i += (long)nb * TPB) {
      int mat, k4, e, E;
      if (i < 32768) {
        mat = (int)(i >> 12); int rem = (int)i & 4095; k4 = rem >> 7; e = rem & 127; E = 128;
      } else {
        long i2 = i - 32768; mat = 8 + (int)(i2 >> 14); int rem = (int)i2 & 16383;
        k4 = rem >> 9; e = rem & 511; E = 512;
      }
      const float* Wm = p.Wsrc[mat];
      float4 v;
      v.x = Wm[(4 * k4 + 0) * E + e];
      v.y = Wm[(4 * k4 + 1) * E + e];
      v.z = Wm[(4 * k4 + 2) * E + e];
      v.w = Wm[(4 * k4 + 3) * E + e];
      *(float4*)&p.Wt[mat][((long)(k4 * E + e)) * 4] = v;
    }
  }
  __threadfence();
  grid.sync();

  int nlv = p.n_levels[0];
  if (nlv < 0) nlv = 0;
  if (nlv > SMAX) nlv = SMAX;

  for (int lv = 0; lv < nlv; ++lv) {
    const int beg = p.level_off[lv], end = p.level_off[lv + 1];
    const int M = end - beg;
    const int nmt64 = (M + 63) >> 6;
    const int nmt16 = (M + 15) >> 4;

    // ================= PH1: EH / ET / CADJH / CADJT / COPY =================
    for (int job = bid; job < 5 * nmt64; job += nb) {
      const int type = job / nmt64;
      const int mt = job - type * nmt64;
      const int r0 = mt << 6;
      __syncthreads();
      if (tid < 64) {
        int r = r0 + tid;
        int s = -1, h = 0, t = 0;
        float dec = 1.0f;
        if (r < M) {
          s = p.order[beg + r]; h = p.heads[s]; t = p.tails[s];
          if (type == 2) dec = expf(-(p.times[s] - p.rt[h]));
          else if (type == 3) dec = expf(-(p.times[s] - p.rt[t]));
        }
        sL[tid] = s; hL[tid] = h; tL[tid] = t; decL[tid] = dec;
      }
      __syncthreads();

      const int e = tid & 127;
      const int rg = tid >> 7;     // 4 rowgroups x 16 rows; rg is wave-uniform

      if (type <= 1) {            // EH / ET : tanh(RepH@W1 + RepT@W2 + b)
        const float* W1 = p.Wt[type ? 2 : 0];
        const float* W2 = p.Wt[type ? 3 : 1];
        const float* bias = type ? p.bet : p.beh;
        float acc[16];
        float bv = bias[e];
#pragma unroll
        for (int j = 0; j < 16; ++j) acc[j] = bv;
        unsigned offs[16];
#pragma unroll
        for (int j = 0; j < 16; ++j)
          offs[j] = (unsigned)__builtin_amdgcn_readfirstlane(hL[rg * 16 + j]) * 128u;
#pragma unroll 2
        for (int k4 = 0; k4 < 32; ++k4) {
          float4 w = *(const float4*)&W1[(k4 * 128 + e) * 4];
#pragma unroll
          for (int j = 0; j < 16; ++j) {
            float4 a = *(const float4*)&p.node_rep[(size_t)offs[j] + (k4 << 2)];
            FMA4(j, a, w);
          }
        }
#pragma unroll
        for (int j = 0; j < 16; ++j)
          offs[j] = (unsigned)__builtin_amdgcn_readfirstlane(tL[rg * 16 + j]) * 128u;
#pragma unroll 2
        for (int k4 = 0; k4 < 32; ++k4) {
          float4 w = *(const float4*)&W2[(k4 * 128 + e) * 4];
#pragma unroll
          for (int j = 0; j < 16; ++j) {
            float4 a = *(const float4*)&p.node_rep[(size_t)offs[j] + (k4 << 2)];
            FMA4(j, a, w);
          }
        }
        float* dst = type ? p.ET : p.EH;
#pragma unroll
        for (int j = 0; j < 16; ++j) {
          int r = r0 + rg * 16 + j;
          if (r < M) dst[(size_t)r * 128 + e] = tanhf(acc[j]);
        }
      } else if (type <= 3) {     // CADJ: c - cs + cs*dec, cs = tanh(c@Wd + bd)
        const float* W = p.Wt[type == 2 ? 4 : 5];
        const float* bias = (type == 2) ? p.bdh : p.bdt;
        const float* ctab = (type == 2) ? p.cell_head : p.cell_tail;
        const int* nodeL = (type == 2) ? hL : tL;
        float acc[16];
        float bv = bias[e];
#pragma unroll
        for (int j = 0; j < 16; ++j) acc[j] = bv;
        unsigned offs[16];
#pragma unroll
        for (int j = 0; j < 16; ++j)
          offs[j] = (unsigned)__builtin_amdgcn_readfirstlane(nodeL[rg * 16 + j]) * 128u;
#pragma unroll 2
        for (int k4 = 0; k4 < 32; ++k4) {
          float4 w = *(const float4*)&W[(k4 * 128 + e) * 4];
#pragma unroll
          for (int j = 0; j < 16; ++j) {
            float4 a = *(const float4*)&ctab[(size_t)offs[j] + (k4 << 2)];
            FMA4(j, a, w);
          }
        }
        float* dst = (type == 2) ? p.CADJH : p.CADJT;
#pragma unroll
        for (int j = 0; j < 16; ++j) {
          int lr = rg * 16 + j, r = r0 + lr;
          if (r < M) {
            float cs = tanhf(acc[j]);
            float c = ctab[(size_t)offs[j] + e];
            dst[(size_t)r * 128 + e] = c - cs + cs * decL[lr];
          }
        }
      } else {                    // COPY: out (pre-update reps) + old-hidden snapshots
#pragma unroll 4
        for (int j = 0; j < 16; ++j) {
          int lr = rg * 16 + j, r = r0 + lr;
          if (r >= M) continue;
          int s = sL[lr];
          unsigned ho = (unsigned)hL[lr] * 128u, to = (unsigned)tL[lr] * 128u;
          p.out[(size_t)s * 128 + e] = p.node_rep[(size_t)ho + e];
          p.out[(size_t)(p.S + s) * 128 + e] = p.node_rep[(size_t)to + e];
          p.HTHold[(size_t)r * 128 + e] = p.hidden_tail[(size_t)ho + e];
          p.HHTold[(size_t)r * 128 + e] = p.hidden_head[(size_t)to + e];
        }
      }
    }
    __threadfence();
    grid.sync();

    // ================= PH2: Z = x@Wx + h@Wh + b; gates; scatter c/h/rt ======
    for (int job = bid; job < 2 * nmt16; job += nb) {
      const int side = job & 1;
      const int mt = job >> 1;
      const int r0 = mt << 4;
      __syncthreads();
      if (tid < 16) {
        int r = r0 + tid;
        int s = -1, h = 0, t = 0;
        if (r < M) { s = p.order[beg + r]; h = p.heads[s]; t = p.tails[s]; }
        sL[tid] = s; hL[tid] = h; tL[tid] = t;
      }
      __syncthreads();

      const int c = tid;           // 0..511
      const float* TX = p.Wt[side ? 10 : 8];
      const float* TH = p.Wt[side ? 11 : 9];
      const float* bias = side ? p.bt : p.bh;
      const float* X = side ? p.ET : p.EH;
      float* ctab = side ? p.cell_tail : p.cell_head;
      float* htab = side ? p.hidden_tail : p.hidden_head;
      const int* nodeL = side ? tL : hL;

      float acc[16];
      float bv = bias[c];
#pragma unroll
      for (int j = 0; j < 16; ++j) acc[j] = bv;

#pragma unroll 2
      for (int k4 = 0; k4 < 32; ++k4) {
        float4 w = *(const float4*)&TX[((long)(k4 * 512 + c)) * 4];
#pragma unroll
        for (int j = 0; j < 16; ++j) {
          float4 a = *(const float4*)&X[(size_t)(r0 + j) * 128 + (k4 << 2)];
          FMA4(j, a, w);
        }
      }
      unsigned offs[16];
#pragma unroll
      for (int j = 0; j < 16; ++j)
        offs[j] = (unsigned)__builtin_amdgcn_readfirstlane(nodeL[j]) * 128u;
#pragma unroll 2
      for (int k4 = 0; k4 < 32; ++k4) {
        float4 w = *(const float4*)&TH[((long)(k4 * 512 + c)) * 4];
#pragma unroll
        for (int j = 0; j < 16; ++j) {
          float4 a = *(const float4*)&htab[(size_t)offs[j] + (k4 << 2)];
          FMA4(j, a, w);
        }
      }
#pragma unroll
      for (int j = 0; j < 16; ++j) Z[j * 512 + c] = acc[j];
      __syncthreads();

      const float* cadjB = side ? p.CADJT : p.CADJH;
      float* hnB = side ? p.HNT : p.HNH;
#pragma unroll
      for (int q = 0; q < 4; ++q) {
        int idx = q * 512 + tid;
        int lr = idx >> 7, e2 = idx & 127;
        int r = r0 + lr;
        if (r < M) {
          float iv = sigmoidf(Z[lr * 512 + e2]);
          float fv = sigmoidf(Z[lr * 512 + 128 + e2]);
          float ov = sigmoidf(Z[lr * 512 + 256 + e2]);
          float gv = tanhf(Z[lr * 512 + 384 + e2]);
          float cadj = cadjB[(size_t)r * 128 + e2];
          float cn = fv * cadj + iv * gv;
          float hn = ov * tanhf(cn);
          unsigned no = (unsigned)nodeL[lr] * 128u;
          ctab[(size_t)no + e2] = cn;
          htab[(size_t)no + e2] = hn;
          hnB[(size_t)r * 128 + e2] = hn;
        }
      }
      if (tid < 16) {
        int r = r0 + tid;
        if (r < M) p.rt[nodeL[tid]] = p.times[sL[tid]];
      }
    }
    __threadfence();
    grid.sync();

    // ================= PH3: combiner + rep scatter ==========================
    for (int job = bid; job < 2 * nmt64; job += nb) {
      const int side = job & 1;
      const int mt = job >> 1;
      const int r0 = mt << 6;
      __syncthreads();
      if (tid < 64) {
        int r = r0 + tid;
        int s = -1, h = 0, t = 0;
        if (r < M) { s = p.order[beg + r]; h = p.heads[s]; t = p.tails[s]; }
        sL[tid] = s; hL[tid] = h; tL[tid] = t;
      }
      __syncthreads();

      const int e = tid & 127;
      const int rg = tid >> 7;
      const float* A1 = side ? p.HHTold : p.HNH;    // @ Wc1
      const float* A2 = side ? p.HNT : p.HTHold;    // @ Wc2
      const float* W1 = p.Wt[6];
      const float* W2 = p.Wt[7];
      float acc[16];
#pragma unroll
      for (int j = 0; j < 16; ++j) acc[j] = 0.0f;

#pragma unroll 2
      for (int k4 = 0; k4 < 32; ++k4) {
        float4 w = *(const float4*)&W1[(k4 * 128 + e) * 4];
#pragma unroll
        for (int j = 0; j < 16; ++j) {
          float4 a = *(const float4*)&A1[(size_t)(r0 + rg * 16 + j) * 128 + (k4 << 2)];
          FMA4(j, a, w);
        }
      }
#pragma unroll 2
      for (int k4 = 0; k4 < 32; ++k4) {
        float4 w = *(const float4*)&W2[(k4 * 128 + e) * 4];
#pragma unroll
        for (int j = 0; j < 16; ++j) {
          float4 a = *(const float4*)&A2[(size_t)(r0 + rg * 16 + j) * 128 + (k4 << 2)];
          FMA4(j, a, w);
        }
      }
#pragma unroll
      for (int j = 0; j < 16; ++j) {
        int lr = rg * 16 + j, r = r0 + lr;
        if (r < M) {
          int h = hL[lr], t = tL[lr];
          if (side) p.node_rep[(size_t)t * 128 + e] = tanhf(acc[j]);
          else if (h != t) p.node_rep[(size_t)h * 128 + e] = tanhf(acc[j]);
        }
      }
    }
    __threadfence();
    grid.sync();
  }
}

// ---------------------------------------------------------------------------
extern "C" void kernel_launch(void* const* d_in, const int* in_sizes, int n_in,
                              void* d_out, int out_size, void* d_ws, size_t ws_size,
                              hipStream_t stream) {
  const int* heads = (const int*)d_in[0];
  const int* tails = (const int*)d_in[1];
  const float* times = (const float*)d_in[2];
  float* node_rep    = (float*)d_in[3];
  float* cell_head   = (float*)d_in[4];
  float* hidden_head = (float*)d_in[5];
  float* cell_tail   = (float*)d_in[6];
  float* hidden_tail = (float*)d_in[7];

  const int S = in_sizes[0];
  const int N = in_sizes[3] / DD;

  char* ws = (char*)d_ws;
  size_t off = 0;
  float* rt = (float*)ws;
  off = (((size_t)N * 4) + 511) & ~(size_t)511;
  int* order     = (int*)(ws + off); off += (size_t)SMAX * 4;
  int* level_off = (int*)(ws + off); off += (size_t)(SMAX + 1) * 4;
  int* n_levels  = (int*)(ws + off); off += 64 * 4;
  int* ph        = (int*)(ws + off); off += (size_t)SMAX * 4;
  int* pt        = (int*)(ws + off); off += (size_t)SMAX * 4;
  off = (off + 255) & ~(size_t)255;

  PParams p;
  p.heads = heads; p.tails = tails; p.times = times;
  p.node_rep = node_rep; p.cell_head = cell_head; p.hidden_head = hidden_head;
  p.cell_tail = cell_tail; p.hidden_tail = hidden_tail;
  p.beh = (const float*)d_in[10]; p.bet = (const float*)d_in[13];
  p.bh  = (const float*)d_in[16]; p.bt  = (const float*)d_in[21];
  p.bdh = (const float*)d_in[18]; p.bdt = (const float*)d_in[23];
  p.Wsrc[0] = (const float*)d_in[8];   // Weh1
  p.Wsrc[1] = (const float*)d_in[9];   // Weh2
  p.Wsrc[2] = (const float*)d_in[11];  // Wet1
  p.Wsrc[3] = (const float*)d_in[12];  // Wet2
  p.Wsrc[4] = (const float*)d_in[17];  // Wdh
  p.Wsrc[5] = (const float*)d_in[22];  // Wdt
  p.Wsrc[6] = (const float*)d_in[24];  // Wc1
  p.Wsrc[7] = (const float*)d_in[25];  // Wc2
  p.Wsrc[8] = (const float*)d_in[14];  // Wxh
  p.Wsrc[9] = (const float*)d_in[15];  // Whh
  p.Wsrc[10] = (const float*)d_in[19]; // Wxt
  p.Wsrc[11] = (const float*)d_in[20]; // Wht

  for (int m = 0; m < 12; ++m) {
    size_t n = (m < 8) ? 16384 : 65536;
    p.Wt[m] = (float*)(ws + off); off += n * 4;
  }
  p.EH     = (float*)(ws + off); off += (size_t)SMAX * 128 * 4;
  p.ET     = (float*)(ws + off); off += (size_t)SMAX * 128 * 4;
  p.CADJH  = (float*)(ws + off); off += (size_t)SMAX * 128 * 4;
  p.CADJT  = (float*)(ws + off); off += (size_t)SMAX * 128 * 4;
  p.HTHold = (float*)(ws + off); off += (size_t)SMAX * 128 * 4;
  p.HHTold = (float*)(ws + off); off += (size_t)SMAX * 128 * 4;
  p.HNH    = (float*)(ws + off); off += (size_t)SMAX * 128 * 4;
  p.HNT    = (float*)(ws + off); off += (size_t)SMAX * 128 * 4;

  p.out = (float*)d_out; p.rt = rt;
  p.order = order; p.level_off = level_off; p.n_levels = n_levels;
  p.S = S;

  hipMemsetAsync(rt, 0, (size_t)N * 4, stream);
  pred_kernel<<<S, 64, 0, stream>>>(heads, tails, S, ph, pt);
  finalize_kernel<<<1, 1024, 0, stream>>>(S, ph, pt, order, level_off, n_levels);

  void* args[] = { (void*)&p };

  int dev = 0; hipGetDevice(&dev);
  int nCU = 0;
  hipDeviceGetAttribute(&nCU, hipDeviceAttributeMultiprocessorCount, dev);
  if (nCU <= 0) nCU = 256;
  int maxBlkPerCU = 0;
  hipOccupancyMaxActiveBlocksPerMultiprocessor(&maxBlkPerCU, process_kernel, TPB, 0);
  if (maxBlkPerCU < 1) maxBlkPerCU = 1;
  long long cap = (long long)nCU * (long long)maxBlkPerCU;
  int grid = (int)(cap < NBLK_MAX ? cap : NBLK_MAX);
  if (grid < 1) grid = nCU;

  hipError_t err = hipLaunchCooperativeKernel(process_kernel, dim3(grid), dim3(TPB),
                                              args, 0, stream);
  if (err != hipSuccess && grid > 256) {
    err = hipLaunchCooperativeKernel(process_kernel, dim3(256), dim3(TPB), args, 0, stream);
  }
  if (err != hipSuccess && grid > 128) {
    err = hipLaunchCooperativeKernel(process_kernel, dim3(128), dim3(TPB), args, 0, stream);
  }
}

// Round 4
// 1298.713 us; speedup vs baseline: 1.1026x; 1.1026x over previous
//
#include <hip/hip_runtime.h>
#include <hip/hip_cooperative_groups.h>
#include <math.h>

namespace cg = cooperative_groups;

#define DD 128
#define TPB 512
#define SMAX 2048
#define NBLK_MAX 512

__device__ __forceinline__ float sigmoidf(float x) { return 1.0f / (1.0f + expf(-x)); }

// ---------------------------------------------------------------------------
// R9 == R8 resubmit (R8 bench was an infra failure, never measured).
// Single cooperative kernel:
//  - pred + level-finalize merged in (kills ~2 kernel launches of overhead)
//  - level-batched GEMMs keep weight amortization (1 float4 -> 64 FMAs) but
//    A-operands staged in LDS (R7's global broadcast loads were the 1193us
//    regression: 16 serial VMEM broadcasts per k4 at full L2 latency).
//  - __launch_bounds__(512,4): 4 waves/EU -> 2 blocks/CU, VGPR<=128.
// ---------------------------------------------------------------------------
struct PParams {
  const int* heads; const int* tails; const float* times;
  float* node_rep; float* cell_head; float* hidden_head; float* cell_tail; float* hidden_tail;
  const float* beh; const float* bet; const float* bh; const float* bt;
  const float* bdh; const float* bdt;
  const float* Wsrc[12];   // Weh1,Weh2,Wet1,Wet2,Wdh,Wdt,Wc1,Wc2,Wxh,Whh,Wxt,Wht
  float* Wt[12];           // k4-tiled transposed copies
  float* EH; float* ET; float* CADJH; float* CADJT;
  float* HTHold; float* HHTold; float* HNH; float* HNT;
  float* out; float* rt;
  int* order; int* level_off; int* n_levels; int* ph; int* pt;
  int S;
};

// GEMM over a 64-row LDS tile: thread = (e, rowgroup rg of 16 rows)
#define GEMM64(Wp) \
  _Pragma("unroll 2") \
  for (int k4 = 0; k4 < 32; ++k4) { \
    float4 w = *(const float4*)&(Wp)[(k4 * 128 + e) * 4]; \
    _Pragma("unroll") \
    for (int j = 0; j < 16; ++j) { \
      float4 a = *(const float4*)&S_[(rg * 16 + j) * 128 + (k4 << 2)]; \
      acc[j] += a.x * w.x + a.y * w.y + a.z * w.z + a.w * w.w; \
    } \
  }

// stage 64 rows (by node index) into S_[64][128]
#define STAGE_IDX(tab, nodeA) \
  _Pragma("unroll") \
  for (int q = 0; q < 4; ++q) { \
    int f = q * TPB + tid; \
    int row = f >> 5, c4 = (f & 31) << 2; \
    *(float4*)&S_[row * 128 + c4] = \
        *(const float4*)&(tab)[(size_t)(nodeA)[row] * 128 + c4]; \
  }

// stage 64 contiguous rows (src pre-offset by r0*128)
#define STAGE_SEQ(src) \
  _Pragma("unroll") \
  for (int q = 0; q < 4; ++q) { \
    int f = q * TPB + tid; \
    int row = f >> 5, c4 = (f & 31) << 2; \
    *(float4*)&S_[row * 128 + c4] = *(const float4*)&(src)[(size_t)row * 128 + c4]; \
  }

__global__ __launch_bounds__(TPB, 4) void process_kernel(PParams p) {
  cg::grid_group grid = cg::this_grid();
  const int tid = threadIdx.x;
  const int bid = (int)blockIdx.x;
  const int nb  = (int)gridDim.x;
  const int S = p.S;

  __shared__ __align__(16) float S_[8192];   // 32 KB staging / Z / finalize scratch
  __shared__ int sL[64], hL[64], tL[64];
  __shared__ float decL[64];
  __shared__ int sh_changed, sh_maxl;

  // ---- Phase -1a: predecessors (wave-per-j across all blocks)
  {
    const int wv = tid >> 6, lane = tid & 63;
    for (int j = bid * 8 + wv; j < S; j += nb * 8) {
      const int myh = p.heads[j], myt = p.tails[j];
      int mph = -1, mpt = -1;
      for (int i = lane; i < j; i += 64) {
        int a = p.heads[i], b = p.tails[i];
        if (a == myh || b == myh) mph = i;
        if (a == myt || b == myt) mpt = i;
      }
#pragma unroll
      for (int off = 32; off > 0; off >>= 1) {
        mph = max(mph, __shfl_down(mph, off));
        mpt = max(mpt, __shfl_down(mpt, off));
      }
      if (lane == 0) { p.ph[j] = mph; p.pt[j] = mpt; }
    }
  }

  // ---- Phase -1b: weight transpose into k4-tiled T[(k4*E+e)*4 + j]
  {
    for (int i = bid * TPB + tid; i < 98304; i += nb * TPB) {
      int mat, k4, e, E;
      if (i < 32768) {
        mat = i >> 12; int rem = i & 4095; k4 = rem >> 7; e = rem & 127; E = 128;
      } else {
        int i2 = i - 32768; mat = 8 + (i2 >> 14); int rem = i2 & 16383;
        k4 = rem >> 9; e = rem & 511; E = 512;
      }
      const float* Wm = p.Wsrc[mat];
      float4 v;
      v.x = Wm[(4 * k4 + 0) * E + e];
      v.y = Wm[(4 * k4 + 1) * E + e];
      v.z = Wm[(4 * k4 + 2) * E + e];
      v.w = Wm[(4 * k4 + 3) * E + e];
      *(float4*)&p.Wt[mat][(size_t)(k4 * E + e) * 4] = v;
    }
  }
  __threadfence();
  grid.sync();

  // ---- Phase -1c: level finalize (block 0 only; S_ reused as int scratch)
  if (bid == 0) {
    int* lvl = (int*)S_;
    int* ph2 = lvl + SMAX;
    int* pt2 = ph2 + SMAX;
    int* cnt = pt2 + SMAX;
    for (int j = tid; j < S; j += TPB) { ph2[j] = p.ph[j]; pt2[j] = p.pt[j]; lvl[j] = 1; }
    __syncthreads();
    for (int it = 0; it < S + 2; ++it) {
      if (tid == 0) sh_changed = 0;
      __syncthreads();
      for (int j = tid; j < S; j += TPB) {
        int l = 1;
        int a = ph2[j]; if (a >= 0) l = lvl[a] + 1;
        int b = pt2[j]; if (b >= 0) { int lb = lvl[b] + 1; if (lb > l) l = lb; }
        if (l != lvl[j]) { lvl[j] = l; sh_changed = 1; }
      }
      __syncthreads();
      if (!sh_changed) break;
      __syncthreads();
    }
    if (tid == 0) sh_maxl = 0;
    __syncthreads();
    for (int j = tid; j < S; j += TPB) atomicMax(&sh_maxl, lvl[j]);
    __syncthreads();
    const int Mlvl = sh_maxl;
    for (int l = tid; l < Mlvl; l += TPB) cnt[l] = 0;
    __syncthreads();
    for (int j = tid; j < S; j += TPB) atomicAdd(&cnt[lvl[j] - 1], 1);
    __syncthreads();
    if (tid == 0) {
      int run = 0; p.level_off[0] = 0;
      for (int l = 0; l < Mlvl; ++l) { run += cnt[l]; p.level_off[l + 1] = run; }
      p.n_levels[0] = Mlvl;
    }
    __syncthreads();
    for (int l = tid; l < Mlvl; l += TPB) cnt[l] = 0;
    __syncthreads();
    for (int j = tid; j < S; j += TPB) {
      int lv2 = lvl[j] - 1;
      int pos = p.level_off[lv2] + atomicAdd(&cnt[lv2], 1);
      p.order[pos] = j;
    }
  }
  __threadfence();
  grid.sync();

  int nlv = p.n_levels[0];
  if (nlv < 0) nlv = 0;
  if (nlv > SMAX) nlv = SMAX;

  for (int lv = 0; lv < nlv; ++lv) {
    const int beg = p.level_off[lv], end = p.level_off[lv + 1];
    const int M = end - beg;
    const int nmt64 = (M + 63) >> 6;
    const int nmt16 = (M + 15) >> 4;

    // ================= PH1: EH / ET / CADJH / CADJT / COPY =================
    for (int job = bid; job < 5 * nmt64; job += nb) {
      const int type = job / nmt64;
      const int mt = job - type * nmt64;
      const int r0 = mt << 6;
      __syncthreads();
      if (tid < 64) {
        int r = r0 + tid;
        int s = -1, h = 0, t = 0; float dec = 1.0f;
        if (r < M) {
          s = p.order[beg + r]; h = p.heads[s]; t = p.tails[s];
          if (type == 2) dec = expf(-(p.times[s] - p.rt[h]));
          else if (type == 3) dec = expf(-(p.times[s] - p.rt[t]));
        }
        sL[tid] = s; hL[tid] = h; tL[tid] = t; decL[tid] = dec;
      }
      __syncthreads();

      const int e = tid & 127;
      const int rg = tid >> 7;

      if (type <= 1) {            // EH / ET : tanh(RepH@W1 + RepT@W2 + b)
        const float* W1 = p.Wt[type ? 2 : 0];
        const float* W2 = p.Wt[type ? 3 : 1];
        const float* bias = type ? p.bet : p.beh;
        float acc[16];
        float bv = bias[e];
#pragma unroll
        for (int j = 0; j < 16; ++j) acc[j] = bv;
        STAGE_IDX(p.node_rep, hL);
        __syncthreads();
        GEMM64(W1);
        __syncthreads();
        STAGE_IDX(p.node_rep, tL);
        __syncthreads();
        GEMM64(W2);
        float* dst = type ? p.ET : p.EH;
#pragma unroll
        for (int j = 0; j < 16; ++j) {
          int r = r0 + rg * 16 + j;
          if (r < M) dst[(size_t)r * 128 + e] = tanhf(acc[j]);
        }
      } else if (type <= 3) {     // CADJ: c - cs + cs*dec, cs = tanh(c@Wd + bd)
        const float* W = p.Wt[type == 2 ? 4 : 5];
        const float* bias = (type == 2) ? p.bdh : p.bdt;
        const float* ctab = (type == 2) ? p.cell_head : p.cell_tail;
        const int* nodeL = (type == 2) ? hL : tL;
        float acc[16];
        float bv = bias[e];
#pragma unroll
        for (int j = 0; j < 16; ++j) acc[j] = bv;
        STAGE_IDX(ctab, nodeL);
        __syncthreads();
        GEMM64(W);
        float* dst = (type == 2) ? p.CADJH : p.CADJT;
#pragma unroll
        for (int j = 0; j < 16; ++j) {
          int lr = rg * 16 + j, r = r0 + lr;
          if (r < M) {
            float cs = tanhf(acc[j]);
            float c = S_[lr * 128 + e];
            dst[(size_t)r * 128 + e] = c - cs + cs * decL[lr];
          }
        }
      } else {                    // COPY: out + old-hidden snapshots
#pragma unroll 4
        for (int j = 0; j < 16; ++j) {
          int lr = rg * 16 + j, r = r0 + lr;
          if (r >= M) continue;
          int s2 = sL[lr];
          size_t ho = (size_t)hL[lr] * 128u, to = (size_t)tL[lr] * 128u;
          p.out[(size_t)s2 * 128 + e] = p.node_rep[ho + e];
          p.out[(size_t)(S + s2) * 128 + e] = p.node_rep[to + e];
          p.HTHold[(size_t)r * 128 + e] = p.hidden_tail[ho + e];
          p.HHTold[(size_t)r * 128 + e] = p.hidden_head[to + e];
        }
      }
    }
    __threadfence();
    grid.sync();

    // ================= PH2: Z GEMM (16x512 tile) + gates + scatter ==========
    for (int job = bid; job < 2 * nmt16; job += nb) {
      const int side = job & 1;
      const int mt = job >> 1;
      const int r0 = mt << 4;
      __syncthreads();
      if (tid < 16) {
        int r = r0 + tid;
        int s = -1, h = 0, t = 0;
        if (r < M) { s = p.order[beg + r]; h = p.heads[s]; t = p.tails[s]; }
        sL[tid] = s; hL[tid] = h; tL[tid] = t;
      }
      __syncthreads();

      const float* TX = p.Wt[side ? 10 : 8];
      const float* TH = p.Wt[side ? 11 : 9];
      const float* bias = side ? p.bt : p.bh;
      const float* X = side ? p.ET : p.EH;
      float* ctab = side ? p.cell_tail : p.cell_head;
      float* htab = side ? p.hidden_tail : p.hidden_head;
      const int* nodeL = side ? tL : hL;

      // stage X tile (contiguous) -> S_[0..2048), H tile (gather) -> S_[2048..4096)
      {
        int row = tid >> 5, c4 = (tid & 31) << 2;
        *(float4*)&S_[row * 128 + c4] =
            *(const float4*)&X[(size_t)(r0 + row) * 128 + c4];
        *(float4*)&S_[2048 + row * 128 + c4] =
            *(const float4*)&htab[(size_t)nodeL[row] * 128 + c4];
      }
      __syncthreads();

      const int c = tid;
      float acc[16];
      float bv = bias[c];
#pragma unroll
      for (int j = 0; j < 16; ++j) acc[j] = bv;
#pragma unroll 2
      for (int k4 = 0; k4 < 32; ++k4) {
        float4 w = *(const float4*)&TX[(size_t)(k4 * 512 + c) * 4];
#pragma unroll
        for (int j = 0; j < 16; ++j) {
          float4 a = *(const float4*)&S_[j * 128 + (k4 << 2)];
          acc[j] += a.x * w.x + a.y * w.y + a.z * w.z + a.w * w.w;
        }
      }
#pragma unroll 2
      for (int k4 = 0; k4 < 32; ++k4) {
        float4 w = *(const float4*)&TH[(size_t)(k4 * 512 + c) * 4];
#pragma unroll
        for (int j = 0; j < 16; ++j) {
          float4 a = *(const float4*)&S_[2048 + j * 128 + (k4 << 2)];
          acc[j] += a.x * w.x + a.y * w.y + a.z * w.z + a.w * w.w;
        }
      }
      __syncthreads();            // A tiles dead -> reuse S_ as Z[16][512]
#pragma unroll
      for (int j = 0; j < 16; ++j) S_[j * 512 + c] = acc[j];
      __syncthreads();

      const float* cadjB = side ? p.CADJT : p.CADJH;
      float* hnB = side ? p.HNT : p.HNH;
#pragma unroll
      for (int q = 0; q < 4; ++q) {
        int idx = q * TPB + tid;
        int lr = idx >> 7, e2 = idx & 127;
        int r = r0 + lr;
        if (r < M) {
          float iv = sigmoidf(S_[lr * 512 + e2]);
          float fv = sigmoidf(S_[lr * 512 + 128 + e2]);
          float ov = sigmoidf(S_[lr * 512 + 256 + e2]);
          float gv = tanhf(S_[lr * 512 + 384 + e2]);
          float cadj = cadjB[(size_t)r * 128 + e2];
          float cn = fv * cadj + iv * gv;
          float hn = ov * tanhf(cn);
          size_t no = (size_t)nodeL[lr] * 128u;
          ctab[no + e2] = cn;
          htab[no + e2] = hn;
          hnB[(size_t)r * 128 + e2] = hn;
        }
      }
      if (tid < 16) {
        int r = r0 + tid;
        if (r < M) p.rt[nodeL[tid]] = p.times[sL[tid]];
      }
    }
    __threadfence();
    grid.sync();

    // ================= PH3: combiner + rep scatter ==========================
    for (int job = bid; job < 2 * nmt64; job += nb) {
      const int side = job & 1;
      const int mt = job >> 1;
      const int r0 = mt << 6;
      __syncthreads();
      if (tid < 64) {
        int r = r0 + tid;
        int h = 0, t = 0;
        if (r < M) { int s2 = p.order[beg + r]; h = p.heads[s2]; t = p.tails[s2]; }
        hL[tid] = h; tL[tid] = t;
      }
      __syncthreads();

      const int e = tid & 127;
      const int rg = tid >> 7;
      const float* A1 = (side ? p.HHTold : p.HNH) + (size_t)r0 * 128;
      const float* A2 = (side ? p.HNT : p.HTHold) + (size_t)r0 * 128;
      const float* W1 = p.Wt[6];
      const float* W2 = p.Wt[7];
      float acc[16];
#pragma unroll
      for (int j = 0; j < 16; ++j) acc[j] = 0.0f;
      STAGE_SEQ(A1);
      __syncthreads();
      GEMM64(W1);
      __syncthreads();
      STAGE_SEQ(A2);
      __syncthreads();
      GEMM64(W2);
#pragma unroll
      for (int j = 0; j < 16; ++j) {
        int lr = rg * 16 + j, r = r0 + lr;
        if (r < M) {
          int h = hL[lr], t = tL[lr];
          if (side) p.node_rep[(size_t)t * 128 + e] = tanhf(acc[j]);
          else if (h != t) p.node_rep[(size_t)h * 128 + e] = tanhf(acc[j]);
        }
      }
    }
    __threadfence();
    grid.sync();
  }
}

// ---------------------------------------------------------------------------
extern "C" void kernel_launch(void* const* d_in, const int* in_sizes, int n_in,
                              void* d_out, int out_size, void* d_ws, size_t ws_size,
                              hipStream_t stream) {
  const int* heads = (const int*)d_in[0];
  const int* tails = (const int*)d_in[1];
  const float* times = (const float*)d_in[2];
  float* node_rep    = (float*)d_in[3];
  float* cell_head   = (float*)d_in[4];
  float* hidden_head = (float*)d_in[5];
  float* cell_tail   = (float*)d_in[6];
  float* hidden_tail = (float*)d_in[7];

  const int S = in_sizes[0];
  const int N = in_sizes[3] / DD;

  char* ws = (char*)d_ws;
  size_t off = 0;
  float* rt = (float*)ws;
  off = (((size_t)N * 4) + 511) & ~(size_t)511;
  int* order     = (int*)(ws + off); off += (size_t)SMAX * 4;
  int* level_off = (int*)(ws + off); off += (size_t)(SMAX + 1) * 4;
  int* n_levels  = (int*)(ws + off); off += 64 * 4;
  int* ph        = (int*)(ws + off); off += (size_t)SMAX * 4;
  int* pt        = (int*)(ws + off); off += (size_t)SMAX * 4;
  off = (off + 255) & ~(size_t)255;

  PParams p;
  p.heads = heads; p.tails = tails; p.times = times;
  p.node_rep = node_rep; p.cell_head = cell_head; p.hidden_head = hidden_head;
  p.cell_tail = cell_tail; p.hidden_tail = hidden_tail;
  p.beh = (const float*)d_in[10]; p.bet = (const float*)d_in[13];
  p.bh  = (const float*)d_in[16]; p.bt  = (const float*)d_in[21];
  p.bdh = (const float*)d_in[18]; p.bdt = (const float*)d_in[23];
  p.Wsrc[0] = (const float*)d_in[8];   // Weh1
  p.Wsrc[1] = (const float*)d_in[9];   // Weh2
  p.Wsrc[2] = (const float*)d_in[11];  // Wet1
  p.Wsrc[3] = (const float*)d_in[12];  // Wet2
  p.Wsrc[4] = (const float*)d_in[17];  // Wdh
  p.Wsrc[5] = (const float*)d_in[22];  // Wdt
  p.Wsrc[6] = (const float*)d_in[24];  // Wc1
  p.Wsrc[7] = (const float*)d_in[25];  // Wc2
  p.Wsrc[8] = (const float*)d_in[14];  // Wxh
  p.Wsrc[9] = (const float*)d_in[15];  // Whh
  p.Wsrc[10] = (const float*)d_in[19]; // Wxt
  p.Wsrc[11] = (const float*)d_in[20]; // Wht

  for (int m = 0; m < 12; ++m) {
    size_t n = (m < 8) ? 16384 : 65536;
    p.Wt[m] = (float*)(ws + off); off += n * 4;
  }
  p.EH     = (float*)(ws + off); off += (size_t)SMAX * 128 * 4;
  p.ET     = (float*)(ws + off); off += (size_t)SMAX * 128 * 4;
  p.CADJH  = (float*)(ws + off); off += (size_t)SMAX * 128 * 4;
  p.CADJT  = (float*)(ws + off); off += (size_t)SMAX * 128 * 4;
  p.HTHold = (float*)(ws + off); off += (size_t)SMAX * 128 * 4;
  p.HHTold = (float*)(ws + off); off += (size_t)SMAX * 128 * 4;
  p.HNH    = (float*)(ws + off); off += (size_t)SMAX * 128 * 4;
  p.HNT    = (float*)(ws + off); off += (size_t)SMAX * 128 * 4;

  p.out = (float*)d_out; p.rt = rt;
  p.order = order; p.level_off = level_off; p.n_levels = n_levels;
  p.ph = ph; p.pt = pt;
  p.S = S;

  hipMemsetAsync(rt, 0, (size_t)N * 4, stream);

  void* args[] = { (void*)&p };

  int dev = 0; hipGetDevice(&dev);
  int nCU = 0;
  hipDeviceGetAttribute(&nCU, hipDeviceAttributeMultiprocessorCount, dev);
  if (nCU <= 0) nCU = 256;
  int maxBlkPerCU = 0;
  if (hipOccupancyMaxActiveBlocksPerMultiprocessor(&maxBlkPerCU, process_kernel, TPB, 0)
      != hipSuccess || maxBlkPerCU < 1)
    maxBlkPerCU = 1;
  long long cap = (long long)nCU * (long long)maxBlkPerCU;
  int grid = (int)(cap < NBLK_MAX ? cap : NBLK_MAX);
  if (grid < 1) grid = nCU;

  hipError_t err = hipLaunchCooperativeKernel(process_kernel, dim3(grid), dim3(TPB),
                                              args, 0, stream);
  if (err != hipSuccess && grid > 256) {
    err = hipLaunchCooperativeKernel(process_kernel, dim3(256), dim3(TPB), args, 0, stream);
    grid = 256;
  }
  if (err != hipSuccess && grid > 128) {
    err = hipLaunchCooperativeKernel(process_kernel, dim3(128), dim3(TPB), args, 0, stream);
    grid = 128;
  }
  if (err != hipSuccess && grid > 64) {
    err = hipLaunchCooperativeKernel(process_kernel, dim3(64), dim3(TPB), args, 0, stream);
  }
}

// Round 5
// 748.860 us; speedup vs baseline: 1.9122x; 1.7343x over previous
//
#include <hip/hip_runtime.h>
#include <hip/hip_cooperative_groups.h>
#include <math.h>

namespace cg = cooperative_groups;

#define DD 128
#define G 8
#define TPB 512
#define SMAX 2048
#define NBLK_MAX 512

__device__ __forceinline__ float sigmoidf(float x) { return 1.0f / (1.0f + expf(-x)); }

// ---------------------------------------------------------------------------
// R10: R6 dataflow (all per-step state LDS-resident, ONE grid.sync per level)
//  + k4-transposed float4 weight loads (4x fewer weight instrs, unroll-4 MLP)
//  + in-kernel pred/finalize preamble (saves 2 launches; validated in R9)
//  + grid 512 (2 blocks/CU, 4 waves/SIMD TLP).
// R9 lesson: NEVER route per-level intermediates through global memory —
// cross-XCD fence writebacks turned 20 MB of traffic into 80 MB at 61 GB/s.
// ---------------------------------------------------------------------------
struct PParams {
  const int* heads; const int* tails; const float* times;
  float* node_rep; float* cell_head; float* hidden_head; float* cell_tail; float* hidden_tail;
  const float* beh; const float* bet; const float* bh; const float* bt;
  const float* bdh; const float* bdt;
  const float* Wsrc[12];   // Weh1,Weh2,Wet1,Wet2,Wdh,Wdt,Wc1,Wc2,Wxh,Whh,Wxt,Wht
  float* Wt[12];           // k4-tiled: Wt[m][(k4*E+e)*4+j] = W[4k4+j][e]
  float* out; float* rt;
  int* order; int* level_off; int* n_levels; int* ph; int* pt;
  int S;
};

__global__ __launch_bounds__(TPB, 4) void process_kernel(PParams p) {
  cg::grid_group grid = cg::this_grid();
  const int tid = threadIdx.x;
  const int bid = (int)blockIdx.x;
  const int nb  = (int)gridDim.x;
  const int Sn  = p.S;
  const int b0  = (bid * 7) & 31;    // per-block k4 stagger (wave-uniform)

  __shared__ __align__(16) float S_[16384];   // 64 KB
  __shared__ int sIdx[G], hIdx[G], tIdx[G];
  __shared__ float tmv[G], decHs[G], decTs[G];
  __shared__ int sh_changed, sh_maxl;

  const int O_REPH = 0,    O_REPT = 1024, O_CHS = 2048, O_CTS = 3072;   // dead after A
  const int O_ZH   = 0,    O_ZT   = 4096;                                // born in B
  const int O_HHS  = 8192, O_HTS  = 9216, O_HTH = 10240, O_HHT = 11264;  // persistent
  const int O_EH   = 12288, O_ET  = 13312;                               // edge==nh
  const int O_CAH  = 14336, O_CAT = 15360;                               // cadj

  // ---- pred: wave-per-j
  {
    const int wv = tid >> 6, lane = tid & 63;
    for (int j = bid * 8 + wv; j < Sn; j += nb * 8) {
      const int myh = p.heads[j], myt = p.tails[j];
      int mph = -1, mpt = -1;
      for (int i = lane; i < j; i += 64) {
        int a = p.heads[i], b = p.tails[i];
        if (a == myh || b == myh) mph = i;
        if (a == myt || b == myt) mpt = i;
      }
#pragma unroll
      for (int off = 32; off > 0; off >>= 1) {
        mph = max(mph, __shfl_down(mph, off));
        mpt = max(mpt, __shfl_down(mpt, off));
      }
      if (lane == 0) { p.ph[j] = mph; p.pt[j] = mpt; }
    }
  }

  // ---- weight transpose into k4 layout
  {
    for (int i = bid * TPB + tid; i < 98304; i += nb * TPB) {
      int mat, k4, e, E;
      if (i < 32768) {
        mat = i >> 12; int rem = i & 4095; k4 = rem >> 7; e = rem & 127; E = 128;
      } else {
        int i2 = i - 32768; mat = 8 + (i2 >> 14); int rem = i2 & 16383;
        k4 = rem >> 9; e = rem & 511; E = 512;
      }
      const float* Wm = p.Wsrc[mat];
      float4 v;
      v.x = Wm[(4 * k4 + 0) * E + e];
      v.y = Wm[(4 * k4 + 1) * E + e];
      v.z = Wm[(4 * k4 + 2) * E + e];
      v.w = Wm[(4 * k4 + 3) * E + e];
      *(float4*)&p.Wt[mat][(size_t)(k4 * E + e) * 4] = v;
    }
  }
  __threadfence();
  grid.sync();

  // ---- level finalize (block 0; S_ as int scratch)
  if (bid == 0) {
    int* lvl = (int*)S_;
    int* ph2 = lvl + SMAX;
    int* pt2 = ph2 + SMAX;
    int* cnt = pt2 + SMAX;
    for (int j = tid; j < Sn; j += TPB) { ph2[j] = p.ph[j]; pt2[j] = p.pt[j]; lvl[j] = 1; }
    __syncthreads();
    for (int it = 0; it < Sn + 2; ++it) {
      if (tid == 0) sh_changed = 0;
      __syncthreads();
      for (int j = tid; j < Sn; j += TPB) {
        int l = 1;
        int a = ph2[j]; if (a >= 0) l = lvl[a] + 1;
        int b = pt2[j]; if (b >= 0) { int lb = lvl[b] + 1; if (lb > l) l = lb; }
        if (l != lvl[j]) { lvl[j] = l; sh_changed = 1; }
      }
      __syncthreads();
      if (!sh_changed) break;
      __syncthreads();
    }
    if (tid == 0) sh_maxl = 0;
    __syncthreads();
    for (int j = tid; j < Sn; j += TPB) atomicMax(&sh_maxl, lvl[j]);
    __syncthreads();
    const int Mlvl = sh_maxl;
    for (int l = tid; l < Mlvl; l += TPB) cnt[l] = 0;
    __syncthreads();
    for (int j = tid; j < Sn; j += TPB) atomicAdd(&cnt[lvl[j] - 1], 1);
    __syncthreads();
    if (tid == 0) {
      int run = 0; p.level_off[0] = 0;
      for (int l = 0; l < Mlvl; ++l) { run += cnt[l]; p.level_off[l + 1] = run; }
      p.n_levels[0] = Mlvl;
    }
    __syncthreads();
    for (int l = tid; l < Mlvl; l += TPB) cnt[l] = 0;
    __syncthreads();
    for (int j = tid; j < Sn; j += TPB) {
      int lv2 = lvl[j] - 1;
      int pos = p.level_off[lv2] + atomicAdd(&cnt[lv2], 1);
      p.order[pos] = j;
    }
  }
  __threadfence();
  grid.sync();

  int nlv = p.n_levels[0];
  if (nlv < 0) nlv = 0;
  if (nlv > SMAX) nlv = SMAX;

  for (int lv = 0; lv < nlv; ++lv) {
    const int beg = p.level_off[lv], end = p.level_off[lv + 1];

    for (int base = beg + bid * G; base < end; base += nb * G) {
      const int ng = min(G, end - base);
      __syncthreads();
      if (tid < ng) {
        int s = p.order[base + tid]; sIdx[tid] = s;
        int h = p.heads[s], t = p.tails[s];
        hIdx[tid] = h; tIdx[tid] = t;
        float tm = p.times[s]; tmv[tid] = tm;
        decHs[tid] = expf(-(tm - p.rt[h]));
        decTs[tid] = expf(-(tm - p.rt[t]));
      }
      __syncthreads();

      // -------- Gather: node rows into [d][8] LDS + emit outputs
      {
        const int d = tid & 127;
        for (int g = tid >> 7; g < ng; g += 4) {
          const size_t oh = (size_t)hIdx[g] * DD + d;
          const size_t ot = (size_t)tIdx[g] * DD + d;
          const int b = d * 8 + g;
          float rh = p.node_rep[oh];
          S_[O_REPH + b] = rh; p.out[(size_t)sIdx[g] * DD + d] = rh;
          S_[O_CHS + b] = p.cell_head[oh];
          S_[O_HHS + b] = p.hidden_head[oh];
          S_[O_HTH + b] = p.hidden_tail[oh];
          float rt_ = p.node_rep[ot];
          S_[O_REPT + b] = rt_; p.out[(size_t)(Sn + sIdx[g]) * DD + d] = rt_;
          S_[O_CTS + b] = p.cell_tail[ot];
          S_[O_HTS + b] = p.hidden_tail[ot];
          S_[O_HHT + b] = p.hidden_head[ot];
        }
      }
      __syncthreads();

      // -------- Phase A: edges (roles 0,1) + decayed cell adjust (roles 2,3)
      {
        const int role = tid >> 7, e = tid & 127;
        if (role <= 1) {
          const float* W1 = p.Wt[role ? 2 : 0];
          const float* W2 = p.Wt[role ? 3 : 1];
          float bv = role ? p.bet[e] : p.beh[e];
          float a[8];
#pragma unroll
          for (int g = 0; g < 8; ++g) a[g] = bv;
#pragma unroll 4
          for (int k4 = 0; k4 < 32; ++k4) {
            const int kk = (k4 + b0) & 31;
            float4 w1 = *(const float4*)&W1[(kk * 128 + e) * 4];
            float4 w2 = *(const float4*)&W2[(kk * 128 + e) * 4];
            const float* w1f = (const float*)&w1;
            const float* w2f = (const float*)&w2;
#pragma unroll
            for (int jj = 0; jj < 4; ++jj) {
              const int d = (kk << 2) + jj;
              const float wa = w1f[jj], wb = w2f[jj];
              float4 rh0 = *(const float4*)&S_[O_REPH + d * 8];
              float4 rh1 = *(const float4*)&S_[O_REPH + d * 8 + 4];
              float4 rt0 = *(const float4*)&S_[O_REPT + d * 8];
              float4 rt1 = *(const float4*)&S_[O_REPT + d * 8 + 4];
              a[0] += rh0.x * wa + rt0.x * wb; a[1] += rh0.y * wa + rt0.y * wb;
              a[2] += rh0.z * wa + rt0.z * wb; a[3] += rh0.w * wa + rt0.w * wb;
              a[4] += rh1.x * wa + rt1.x * wb; a[5] += rh1.y * wa + rt1.y * wb;
              a[6] += rh1.z * wa + rt1.z * wb; a[7] += rh1.w * wa + rt1.w * wb;
            }
          }
          const int dst = role ? O_ET : O_EH;
          float4 o0, o1;
          o0.x = tanhf(a[0]); o0.y = tanhf(a[1]); o0.z = tanhf(a[2]); o0.w = tanhf(a[3]);
          o1.x = tanhf(a[4]); o1.y = tanhf(a[5]); o1.z = tanhf(a[6]); o1.w = tanhf(a[7]);
          *(float4*)&S_[dst + e * 8] = o0;
          *(float4*)&S_[dst + e * 8 + 4] = o1;
        } else {
          const int th = (role == 2);
          const float* W = p.Wt[th ? 4 : 5];
          const int co = th ? O_CHS : O_CTS;
          float bv = th ? p.bdh[e] : p.bdt[e];
          const float* decA = th ? decHs : decTs;
          float a[8];
#pragma unroll
          for (int g = 0; g < 8; ++g) a[g] = bv;
#pragma unroll 4
          for (int k4 = 0; k4 < 32; ++k4) {
            const int kk = (k4 + b0) & 31;
            float4 wd = *(const float4*)&W[(kk * 128 + e) * 4];
            const float* wdf = (const float*)&wd;
#pragma unroll
            for (int jj = 0; jj < 4; ++jj) {
              const int d = (kk << 2) + jj;
              const float wv = wdf[jj];
              float4 c0 = *(const float4*)&S_[co + d * 8];
              float4 c1 = *(const float4*)&S_[co + d * 8 + 4];
              a[0] += c0.x * wv; a[1] += c0.y * wv; a[2] += c0.z * wv; a[3] += c0.w * wv;
              a[4] += c1.x * wv; a[5] += c1.y * wv; a[6] += c1.z * wv; a[7] += c1.w * wv;
            }
          }
          const int dst = th ? O_CAH : O_CAT;
          float o[8];
#pragma unroll
          for (int g = 0; g < 8; ++g) {
            float cs = tanhf(a[g]);
            float c = S_[co + e * 8 + g];
            o[g] = c - cs + cs * decA[g];
          }
          *(float4*)&S_[dst + e * 8]     = make_float4(o[0], o[1], o[2], o[3]);
          *(float4*)&S_[dst + e * 8 + 4] = make_float4(o[4], o[5], o[6], o[7]);
        }
      }
      __syncthreads();

      // -------- Phase B: z = x@Wx + h@Wh + b, both sides, col/thread, 8 accs
      {
        const int c = tid;
        const float* TXh = p.Wt[8];  const float* THh = p.Wt[9];
        const float* TXt = p.Wt[10]; const float* THt = p.Wt[11];
        float bhv = p.bh[c], btv = p.bt[c];
        float h[8], t8[8];
#pragma unroll
        for (int g = 0; g < 8; ++g) { h[g] = bhv; t8[g] = btv; }
#pragma unroll 2
        for (int k4 = 0; k4 < 32; ++k4) {
          const int kk = (k4 + b0) & 31;
          float4 wxh = *(const float4*)&TXh[(size_t)(kk * 512 + c) * 4];
          float4 whh = *(const float4*)&THh[(size_t)(kk * 512 + c) * 4];
          float4 wxt = *(const float4*)&TXt[(size_t)(kk * 512 + c) * 4];
          float4 wht = *(const float4*)&THt[(size_t)(kk * 512 + c) * 4];
          const float* fxh = (const float*)&wxh;
          const float* fhh = (const float*)&whh;
          const float* fxt = (const float*)&wxt;
          const float* fht = (const float*)&wht;
#pragma unroll
          for (int jj = 0; jj < 4; ++jj) {
            const int d = (kk << 2) + jj;
            float4 ex0 = *(const float4*)&S_[O_EH + d * 8];
            float4 ex1 = *(const float4*)&S_[O_EH + d * 8 + 4];
            float4 hx0 = *(const float4*)&S_[O_HHS + d * 8];
            float4 hx1 = *(const float4*)&S_[O_HHS + d * 8 + 4];
            float4 et0 = *(const float4*)&S_[O_ET + d * 8];
            float4 et1 = *(const float4*)&S_[O_ET + d * 8 + 4];
            float4 ht0 = *(const float4*)&S_[O_HTS + d * 8];
            float4 ht1 = *(const float4*)&S_[O_HTS + d * 8 + 4];
            const float a1 = fxh[jj], a2 = fhh[jj], a3 = fxt[jj], a4 = fht[jj];
            h[0] += ex0.x * a1 + hx0.x * a2; h[1] += ex0.y * a1 + hx0.y * a2;
            h[2] += ex0.z * a1 + hx0.z * a2; h[3] += ex0.w * a1 + hx0.w * a2;
            h[4] += ex1.x * a1 + hx1.x * a2; h[5] += ex1.y * a1 + hx1.y * a2;
            h[6] += ex1.z * a1 + hx1.z * a2; h[7] += ex1.w * a1 + hx1.w * a2;
            t8[0] += et0.x * a3 + ht0.x * a4; t8[1] += et0.y * a3 + ht0.y * a4;
            t8[2] += et0.z * a3 + ht0.z * a4; t8[3] += et0.w * a3 + ht0.w * a4;
            t8[4] += et1.x * a3 + ht1.x * a4; t8[5] += et1.y * a3 + ht1.y * a4;
            t8[6] += et1.z * a3 + ht1.z * a4; t8[7] += et1.w * a3 + ht1.w * a4;
          }
        }
        *(float4*)&S_[O_ZH + c * 8]     = make_float4(h[0], h[1], h[2], h[3]);
        *(float4*)&S_[O_ZH + c * 8 + 4] = make_float4(h[4], h[5], h[6], h[7]);
        *(float4*)&S_[O_ZT + c * 8]     = make_float4(t8[0], t8[1], t8[2], t8[3]);
        *(float4*)&S_[O_ZT + c * 8 + 4] = make_float4(t8[4], t8[5], t8[6], t8[7]);
      }
      __syncthreads();

      // -------- Phase C: gates, c/h update, scatter state, rt update
      {
        const int side = tid >> 8, sub = (tid >> 7) & 1, e2 = tid & 127;
        const int zo = side ? O_ZT : O_ZH;
        const int co = side ? O_CAT : O_CAH;
        const int no = side ? O_ET : O_EH;
        float* ctab = side ? p.cell_tail : p.cell_head;
        float* htab = side ? p.hidden_tail : p.hidden_head;
        for (int q = 0; q < 4; ++q) {
          int g = sub + 2 * q;
          if (g >= ng) continue;
          float iv = sigmoidf(S_[zo + e2 * 8 + g]);
          float fv = sigmoidf(S_[zo + (128 + e2) * 8 + g]);
          float ov = sigmoidf(S_[zo + (256 + e2) * 8 + g]);
          float gv = tanhf(S_[zo + (384 + e2) * 8 + g]);
          float cadj = S_[co + e2 * 8 + g];
          float cn = fv * cadj + iv * gv;
          float hn = ov * tanhf(cn);
          S_[no + e2 * 8 + g] = hn;
          int node = side ? tIdx[g] : hIdx[g];
          ctab[(size_t)node * DD + e2] = cn;
          htab[(size_t)node * DD + e2] = hn;
        }
        if (tid < 2 * G) {
          int g = tid & (G - 1);
          if (g < ng) p.rt[(tid >= G) ? tIdx[g] : hIdx[g]] = tmv[g];
        }
      }
      __syncthreads();

      // -------- Phase D: combiner, rep scatter (tail wins on h==t)
      {
        const int role = tid >> 7, e = tid & 127;
        if (role <= 1) {
          const int xo = role ? O_HHT : O_EH;     // @ Wc1
          const int yo = role ? O_ET : O_HTH;     // @ Wc2
          const float* W1 = p.Wt[6];
          const float* W2 = p.Wt[7];
          float a[8];
#pragma unroll
          for (int g = 0; g < 8; ++g) a[g] = 0.f;
#pragma unroll 4
          for (int k4 = 0; k4 < 32; ++k4) {
            const int kk = (k4 + b0) & 31;
            float4 w1 = *(const float4*)&W1[(kk * 128 + e) * 4];
            float4 w2 = *(const float4*)&W2[(kk * 128 + e) * 4];
            const float* w1f = (const float*)&w1;
            const float* w2f = (const float*)&w2;
#pragma unroll
            for (int jj = 0; jj < 4; ++jj) {
              const int d = (kk << 2) + jj;
              const float wa = w1f[jj], wb = w2f[jj];
              float4 x0 = *(const float4*)&S_[xo + d * 8];
              float4 x1 = *(const float4*)&S_[xo + d * 8 + 4];
              float4 y0 = *(const float4*)&S_[yo + d * 8];
              float4 y1 = *(const float4*)&S_[yo + d * 8 + 4];
              a[0] += x0.x * wa + y0.x * wb; a[1] += x0.y * wa + y0.y * wb;
              a[2] += x0.z * wa + y0.z * wb; a[3] += x0.w * wa + y0.w * wb;
              a[4] += x1.x * wa + y1.x * wb; a[5] += x1.y * wa + y1.y * wb;
              a[6] += x1.z * wa + y1.z * wb; a[7] += x1.w * wa + y1.w * wb;
            }
          }
          if (role == 0) {
#pragma unroll
            for (int g = 0; g < 8; ++g)
              if (g < ng && hIdx[g] != tIdx[g])
                p.node_rep[(size_t)hIdx[g] * DD + e] = tanhf(a[g]);
          } else {
#pragma unroll
            for (int g = 0; g < 8; ++g)
              if (g < ng)
                p.node_rep[(size_t)tIdx[g] * DD + e] = tanhf(a[g]);
          }
        }
      }
    }
    __threadfence();
    grid.sync();
  }
}

// ---------------------------------------------------------------------------
extern "C" void kernel_launch(void* const* d_in, const int* in_sizes, int n_in,
                              void* d_out, int out_size, void* d_ws, size_t ws_size,
                              hipStream_t stream) {
  const int* heads = (const int*)d_in[0];
  const int* tails = (const int*)d_in[1];
  const float* times = (const float*)d_in[2];
  float* node_rep    = (float*)d_in[3];
  float* cell_head   = (float*)d_in[4];
  float* hidden_head = (float*)d_in[5];
  float* cell_tail   = (float*)d_in[6];
  float* hidden_tail = (float*)d_in[7];

  const int S = in_sizes[0];
  const int N = in_sizes[3] / DD;

  char* ws = (char*)d_ws;
  size_t off = 0;
  float* rt = (float*)ws;
  off = (((size_t)N * 4) + 511) & ~(size_t)511;
  int* order     = (int*)(ws + off); off += (size_t)SMAX * 4;
  int* level_off = (int*)(ws + off); off += (size_t)(SMAX + 1) * 4;
  int* n_levels  = (int*)(ws + off); off += 64 * 4;
  int* ph        = (int*)(ws + off); off += (size_t)SMAX * 4;
  int* pt        = (int*)(ws + off); off += (size_t)SMAX * 4;
  off = (off + 255) & ~(size_t)255;

  PParams p;
  p.heads = heads; p.tails = tails; p.times = times;
  p.node_rep = node_rep; p.cell_head = cell_head; p.hidden_head = hidden_head;
  p.cell_tail = cell_tail; p.hidden_tail = hidden_tail;
  p.beh = (const float*)d_in[10]; p.bet = (const float*)d_in[13];
  p.bh  = (const float*)d_in[16]; p.bt  = (const float*)d_in[21];
  p.bdh = (const float*)d_in[18]; p.bdt = (const float*)d_in[23];
  p.Wsrc[0] = (const float*)d_in[8];   // Weh1
  p.Wsrc[1] = (const float*)d_in[9];   // Weh2
  p.Wsrc[2] = (const float*)d_in[11];  // Wet1
  p.Wsrc[3] = (const float*)d_in[12];  // Wet2
  p.Wsrc[4] = (const float*)d_in[17];  // Wdh
  p.Wsrc[5] = (const float*)d_in[22];  // Wdt
  p.Wsrc[6] = (const float*)d_in[24];  // Wc1
  p.Wsrc[7] = (const float*)d_in[25];  // Wc2
  p.Wsrc[8] = (const float*)d_in[14];  // Wxh
  p.Wsrc[9] = (const float*)d_in[15];  // Whh
  p.Wsrc[10] = (const float*)d_in[19]; // Wxt
  p.Wsrc[11] = (const float*)d_in[20]; // Wht

  for (int m = 0; m < 12; ++m) {
    size_t n = (m < 8) ? 16384 : 65536;
    p.Wt[m] = (float*)(ws + off); off += n * 4;
  }

  p.out = (float*)d_out; p.rt = rt;
  p.order = order; p.level_off = level_off; p.n_levels = n_levels;
  p.ph = ph; p.pt = pt;
  p.S = S;

  hipMemsetAsync(rt, 0, (size_t)N * 4, stream);

  void* args[] = { (void*)&p };

  int dev = 0; hipGetDevice(&dev);
  int nCU = 0;
  hipDeviceGetAttribute(&nCU, hipDeviceAttributeMultiprocessorCount, dev);
  if (nCU <= 0) nCU = 256;
  int maxBlkPerCU = 0;
  if (hipOccupancyMaxActiveBlocksPerMultiprocessor(&maxBlkPerCU, process_kernel, TPB, 0)
      != hipSuccess || maxBlkPerCU < 1)
    maxBlkPerCU = 1;
  long long cap = (long long)nCU * (long long)maxBlkPerCU;
  int grid = (int)(cap < NBLK_MAX ? cap : NBLK_MAX);
  if (grid < 1) grid = nCU;

  hipError_t err = hipLaunchCooperativeKernel(process_kernel, dim3(grid), dim3(TPB),
                                              args, 0, stream);
  if (err != hipSuccess && grid > 256) {
    err = hipLaunchCooperativeKernel(process_kernel, dim3(256), dim3(TPB), args, 0, stream);
    grid = 256;
  }
  if (err != hipSuccess && grid > 128) {
    err = hipLaunchCooperativeKernel(process_kernel, dim3(128), dim3(TPB), args, 0, stream);
    grid = 128;
  }
  if (err != hipSuccess && grid > 64) {
    err = hipLaunchCooperativeKernel(process_kernel, dim3(64), dim3(TPB), args, 0, stream);
  }
}

// Round 6
// 710.263 us; speedup vs baseline: 2.0161x; 1.0543x over previous
//
#include <hip/hip_runtime.h>
#include <hip/hip_cooperative_groups.h>
#include <math.h>

namespace cg = cooperative_groups;

#define DD 128
#define G 8
#define TPB 512
#define SMAX 2048
#define NBLK_MAX 256

__device__ __forceinline__ float sigmoidf(float x) { return 1.0f / (1.0f + expf(-x)); }

// ---------------------------------------------------------------------------
// R11: R10 structure (in-kernel pred/finalize, k4 float4 weights, LDS-resident
// per-step state, one grid.sync/level) with the measured bottleneck fixed:
// R10's VGPR=64 allocation exposed ~100cy of ds_read_b128 latency on ~2048
// reads/thread/job (VALUBusy 3.4%). All three GEMM phases are now explicitly
// software-pipelined 2-deep in NAMED registers (LDS batch for d+1 issued
// before FMAs of d; weights prefetched one k4 ahead), launch_bounds(512,2)
// so the ~110-125 VGPR schedule is legal, grid=256 (R10 showed 2 blocks/CU
// contends LDS issue and regresses).
// ---------------------------------------------------------------------------
struct PParams {
  const int* heads; const int* tails; const float* times;
  float* node_rep; float* cell_head; float* hidden_head; float* cell_tail; float* hidden_tail;
  const float* beh; const float* bet; const float* bh; const float* bt;
  const float* bdh; const float* bdt;
  const float* Wsrc[12];   // Weh1,Weh2,Wet1,Wet2,Wdh,Wdt,Wc1,Wc2,Wxh,Whh,Wxt,Wht
  float* Wt[12];           // k4-tiled: Wt[m][(k4*E+e)*4+j] = W[4k4+j][e]
  float* out; float* rt;
  int* order; int* level_off; int* n_levels; int* ph; int* pt;
  int S;
};

// 4-float4 LDS batch from two operand planes (o1,o2) at row d
#define RD4(q0,q1,q2,q3,o1,o2,dd) { const int _d8=(dd)*8; \
  q0=*(const float4*)&S_[(o1)+_d8]; q1=*(const float4*)&S_[(o1)+_d8+4]; \
  q2=*(const float4*)&S_[(o2)+_d8]; q3=*(const float4*)&S_[(o2)+_d8+4]; }

#define FMA8(wa,wb,q0,q1,q2,q3) { \
  a0+=q0.x*(wa)+q2.x*(wb); a1+=q0.y*(wa)+q2.y*(wb); \
  a2+=q0.z*(wa)+q2.z*(wb); a3+=q0.w*(wa)+q2.w*(wb); \
  a4+=q1.x*(wa)+q3.x*(wb); a5+=q1.y*(wa)+q3.y*(wb); \
  a6+=q1.z*(wa)+q3.z*(wb); a7+=q1.w*(wa)+q3.w*(wb); }

// 2-float4 LDS batch from one plane
#define RD2(q0,q1,oo,dd) { const int _d8=(dd)*8; \
  q0=*(const float4*)&S_[(oo)+_d8]; q1=*(const float4*)&S_[(oo)+_d8+4]; }

#define FMA8S(wa,q0,q1) { \
  a0+=q0.x*(wa); a1+=q0.y*(wa); a2+=q0.z*(wa); a3+=q0.w*(wa); \
  a4+=q1.x*(wa); a5+=q1.y*(wa); a6+=q1.z*(wa); a7+=q1.w*(wa); }

// Phase B: 8-float4 batch (4 planes) + 32-FMA step
#define RDB(E0,E1,H0,H1,F0,F1,Q0,Q1,dd) { const int _d8=(dd)*8; \
  E0=*(const float4*)&S_[O_EH +_d8]; E1=*(const float4*)&S_[O_EH +_d8+4]; \
  H0=*(const float4*)&S_[O_HHS+_d8]; H1=*(const float4*)&S_[O_HHS+_d8+4]; \
  F0=*(const float4*)&S_[O_ET +_d8]; F1=*(const float4*)&S_[O_ET +_d8+4]; \
  Q0=*(const float4*)&S_[O_HTS+_d8]; Q1=*(const float4*)&S_[O_HTS+_d8+4]; }

#define FMAB(w1_,w2_,w3_,w4_,E0,E1,H0,H1,F0,F1,Q0,Q1) { \
  h0+=E0.x*(w1_)+H0.x*(w2_); h1+=E0.y*(w1_)+H0.y*(w2_); \
  h2+=E0.z*(w1_)+H0.z*(w2_); h3+=E0.w*(w1_)+H0.w*(w2_); \
  h4+=E1.x*(w1_)+H1.x*(w2_); h5+=E1.y*(w1_)+H1.y*(w2_); \
  h6+=E1.z*(w1_)+H1.z*(w2_); h7+=E1.w*(w1_)+H1.w*(w2_); \
  t0+=F0.x*(w3_)+Q0.x*(w4_); t1+=F0.y*(w3_)+Q0.y*(w4_); \
  t2+=F0.z*(w3_)+Q0.z*(w4_); t3+=F0.w*(w3_)+Q0.w*(w4_); \
  t4+=F1.x*(w3_)+Q1.x*(w4_); t5+=F1.y*(w3_)+Q1.y*(w4_); \
  t6+=F1.z*(w3_)+Q1.z*(w4_); t7+=F1.w*(w3_)+Q1.w*(w4_); }

__global__ __launch_bounds__(TPB, 2) void process_kernel(PParams p) {
  cg::grid_group grid = cg::this_grid();
  const int tid = threadIdx.x;
  const int bid = (int)blockIdx.x;
  const int nb  = (int)gridDim.x;
  const int Sn  = p.S;
  const int b0  = (bid * 7) & 31;    // per-block k4 stagger (wave-uniform)

  __shared__ __align__(16) float S_[16384];   // 64 KB
  __shared__ int sIdx[G], hIdx[G], tIdx[G];
  __shared__ float tmv[G], decHs[G], decTs[G];
  __shared__ int sh_changed, sh_maxl;

  const int O_REPH = 0,    O_REPT = 1024, O_CHS = 2048, O_CTS = 3072;   // dead after A
  const int O_ZH   = 0,    O_ZT   = 4096;                                // born in B
  const int O_HHS  = 8192, O_HTS  = 9216, O_HTH = 10240, O_HHT = 11264;  // persistent
  const int O_EH   = 12288, O_ET  = 13312;                               // edge==nh
  const int O_CAH  = 14336, O_CAT = 15360;                               // cadj

  // ---- pred: wave-per-j
  {
    const int wv = tid >> 6, lane = tid & 63;
    for (int j = bid * 8 + wv; j < Sn; j += nb * 8) {
      const int myh = p.heads[j], myt = p.tails[j];
      int mph = -1, mpt = -1;
      for (int i = lane; i < j; i += 64) {
        int a = p.heads[i], b = p.tails[i];
        if (a == myh || b == myh) mph = i;
        if (a == myt || b == myt) mpt = i;
      }
#pragma unroll
      for (int off = 32; off > 0; off >>= 1) {
        mph = max(mph, __shfl_down(mph, off));
        mpt = max(mpt, __shfl_down(mpt, off));
      }
      if (lane == 0) { p.ph[j] = mph; p.pt[j] = mpt; }
    }
  }

  // ---- weight transpose into k4 layout
  {
    for (int i = bid * TPB + tid; i < 98304; i += nb * TPB) {
      int mat, k4, e, E;
      if (i < 32768) {
        mat = i >> 12; int rem = i & 4095; k4 = rem >> 7; e = rem & 127; E = 128;
      } else {
        int i2 = i - 32768; mat = 8 + (i2 >> 14); int rem = i2 & 16383;
        k4 = rem >> 9; e = rem & 511; E = 512;
      }
      const float* Wm = p.Wsrc[mat];
      float4 v;
      v.x = Wm[(4 * k4 + 0) * E + e];
      v.y = Wm[(4 * k4 + 1) * E + e];
      v.z = Wm[(4 * k4 + 2) * E + e];
      v.w = Wm[(4 * k4 + 3) * E + e];
      *(float4*)&p.Wt[mat][(size_t)(k4 * E + e) * 4] = v;
    }
  }
  __threadfence();
  grid.sync();

  // ---- level finalize (block 0; S_ as int scratch)
  if (bid == 0) {
    int* lvl = (int*)S_;
    int* ph2 = lvl + SMAX;
    int* pt2 = ph2 + SMAX;
    int* cnt = pt2 + SMAX;
    for (int j = tid; j < Sn; j += TPB) { ph2[j] = p.ph[j]; pt2[j] = p.pt[j]; lvl[j] = 1; }
    __syncthreads();
    for (int it = 0; it < Sn + 2; ++it) {
      if (tid == 0) sh_changed = 0;
      __syncthreads();
      for (int j = tid; j < Sn; j += TPB) {
        int l = 1;
        int a = ph2[j]; if (a >= 0) l = lvl[a] + 1;
        int b = pt2[j]; if (b >= 0) { int lb = lvl[b] + 1; if (lb > l) l = lb; }
        if (l != lvl[j]) { lvl[j] = l; sh_changed = 1; }
      }
      __syncthreads();
      if (!sh_changed) break;
      __syncthreads();
    }
    if (tid == 0) sh_maxl = 0;
    __syncthreads();
    for (int j = tid; j < Sn; j += TPB) atomicMax(&sh_maxl, lvl[j]);
    __syncthreads();
    const int Mlvl = sh_maxl;
    for (int l = tid; l < Mlvl; l += TPB) cnt[l] = 0;
    __syncthreads();
    for (int j = tid; j < Sn; j += TPB) atomicAdd(&cnt[lvl[j] - 1], 1);
    __syncthreads();
    if (tid == 0) {
      int run = 0; p.level_off[0] = 0;
      for (int l = 0; l < Mlvl; ++l) { run += cnt[l]; p.level_off[l + 1] = run; }
      p.n_levels[0] = Mlvl;
    }
    __syncthreads();
    for (int l = tid; l < Mlvl; l += TPB) cnt[l] = 0;
    __syncthreads();
    for (int j = tid; j < Sn; j += TPB) {
      int lv2 = lvl[j] - 1;
      int pos = p.level_off[lv2] + atomicAdd(&cnt[lv2], 1);
      p.order[pos] = j;
    }
  }
  __threadfence();
  grid.sync();

  int nlv = p.n_levels[0];
  if (nlv < 0) nlv = 0;
  if (nlv > SMAX) nlv = SMAX;

  for (int lv = 0; lv < nlv; ++lv) {
    const int beg = p.level_off[lv], end = p.level_off[lv + 1];

    for (int base = beg + bid * G; base < end; base += nb * G) {
      const int ng = min(G, end - base);
      __syncthreads();
      if (tid < ng) {
        int s = p.order[base + tid]; sIdx[tid] = s;
        int h = p.heads[s], t = p.tails[s];
        hIdx[tid] = h; tIdx[tid] = t;
        float tm = p.times[s]; tmv[tid] = tm;
        decHs[tid] = expf(-(tm - p.rt[h]));
        decTs[tid] = expf(-(tm - p.rt[t]));
      }
      __syncthreads();

      // -------- Gather: node rows into [d][8] LDS + emit outputs
      {
        const int d = tid & 127;
        for (int g = tid >> 7; g < ng; g += 4) {
          const size_t oh = (size_t)hIdx[g] * DD + d;
          const size_t ot = (size_t)tIdx[g] * DD + d;
          const int b = d * 8 + g;
          float rh = p.node_rep[oh];
          S_[O_REPH + b] = rh; p.out[(size_t)sIdx[g] * DD + d] = rh;
          S_[O_CHS + b] = p.cell_head[oh];
          S_[O_HHS + b] = p.hidden_head[oh];
          S_[O_HTH + b] = p.hidden_tail[oh];
          float rt_ = p.node_rep[ot];
          S_[O_REPT + b] = rt_; p.out[(size_t)(Sn + sIdx[g]) * DD + d] = rt_;
          S_[O_CTS + b] = p.cell_tail[ot];
          S_[O_HTS + b] = p.hidden_tail[ot];
          S_[O_HHT + b] = p.hidden_head[ot];
        }
      }
      __syncthreads();

      // -------- Phase A: edges (roles 0,1) + decayed cell adjust (roles 2,3)
      {
        const int role = tid >> 7, e = tid & 127;
        if (role <= 1) {
          const float* W1 = p.Wt[role ? 2 : 0];
          const float* W2 = p.Wt[role ? 3 : 1];
          float bv = role ? p.bet[e] : p.beh[e];
          float a0=bv,a1=bv,a2=bv,a3=bv,a4=bv,a5=bv,a6=bv,a7=bv;
          float4 c0,c1,c2,c3,n0,n1,n2,n3;
          float4 w1v = *(const float4*)&W1[(b0 * 128 + e) * 4];
          float4 w2v = *(const float4*)&W2[(b0 * 128 + e) * 4];
          RD4(c0,c1,c2,c3, O_REPH, O_REPT, b0 * 4);
#pragma unroll 2
          for (int k4 = 0; k4 < 32; ++k4) {
            const int kk = (k4 + b0) & 31, kkn = (k4 + 1 + b0) & 31;
            float4 w1n = *(const float4*)&W1[(kkn * 128 + e) * 4];
            float4 w2n = *(const float4*)&W2[(kkn * 128 + e) * 4];
            const int d4 = kk * 4;
            RD4(n0,n1,n2,n3, O_REPH, O_REPT, d4 + 1); FMA8(w1v.x, w2v.x, c0,c1,c2,c3);
            RD4(c0,c1,c2,c3, O_REPH, O_REPT, d4 + 2); FMA8(w1v.y, w2v.y, n0,n1,n2,n3);
            RD4(n0,n1,n2,n3, O_REPH, O_REPT, d4 + 3); FMA8(w1v.z, w2v.z, c0,c1,c2,c3);
            RD4(c0,c1,c2,c3, O_REPH, O_REPT, kkn * 4); FMA8(w1v.w, w2v.w, n0,n1,n2,n3);
            w1v = w1n; w2v = w2n;
          }
          const int dst = role ? O_ET : O_EH;
          *(float4*)&S_[dst + e * 8]     = make_float4(tanhf(a0), tanhf(a1), tanhf(a2), tanhf(a3));
          *(float4*)&S_[dst + e * 8 + 4] = make_float4(tanhf(a4), tanhf(a5), tanhf(a6), tanhf(a7));
        } else {
          const int th = (role == 2);
          const float* W = p.Wt[th ? 4 : 5];
          const int co = th ? O_CHS : O_CTS;
          float bv = th ? p.bdh[e] : p.bdt[e];
          const float* decA = th ? decHs : decTs;
          float a0=bv,a1=bv,a2=bv,a3=bv,a4=bv,a5=bv,a6=bv,a7=bv;
          float4 c0,c1,n0,n1;
          float4 wv = *(const float4*)&W[(b0 * 128 + e) * 4];
          RD2(c0,c1, co, b0 * 4);
#pragma unroll 2
          for (int k4 = 0; k4 < 32; ++k4) {
            const int kk = (k4 + b0) & 31, kkn = (k4 + 1 + b0) & 31;
            float4 wn = *(const float4*)&W[(kkn * 128 + e) * 4];
            const int d4 = kk * 4;
            RD2(n0,n1, co, d4 + 1); FMA8S(wv.x, c0,c1);
            RD2(c0,c1, co, d4 + 2); FMA8S(wv.y, n0,n1);
            RD2(n0,n1, co, d4 + 3); FMA8S(wv.z, c0,c1);
            RD2(c0,c1, co, kkn * 4); FMA8S(wv.w, n0,n1);
            wv = wn;
          }
          const int dst = th ? O_CAH : O_CAT;
          float cs;
          float4 o0, o1;
          cs = tanhf(a0); o0.x = S_[co + e * 8 + 0] - cs + cs * decA[0];
          cs = tanhf(a1); o0.y = S_[co + e * 8 + 1] - cs + cs * decA[1];
          cs = tanhf(a2); o0.z = S_[co + e * 8 + 2] - cs + cs * decA[2];
          cs = tanhf(a3); o0.w = S_[co + e * 8 + 3] - cs + cs * decA[3];
          cs = tanhf(a4); o1.x = S_[co + e * 8 + 4] - cs + cs * decA[4];
          cs = tanhf(a5); o1.y = S_[co + e * 8 + 5] - cs + cs * decA[5];
          cs = tanhf(a6); o1.z = S_[co + e * 8 + 6] - cs + cs * decA[6];
          cs = tanhf(a7); o1.w = S_[co + e * 8 + 7] - cs + cs * decA[7];
          *(float4*)&S_[dst + e * 8]     = o0;
          *(float4*)&S_[dst + e * 8 + 4] = o1;
        }
      }
      __syncthreads();

      // -------- Phase B: z = x@Wx + h@Wh + b, both sides, col/thread, 16 accs
      {
        const int c = tid;
        const float* TXh = p.Wt[8];  const float* THh = p.Wt[9];
        const float* TXt = p.Wt[10]; const float* THt = p.Wt[11];
        float bhv = p.bh[c], btv = p.bt[c];
        float h0=bhv,h1=bhv,h2=bhv,h3=bhv,h4=bhv,h5=bhv,h6=bhv,h7=bhv;
        float t0=btv,t1=btv,t2=btv,t3=btv,t4=btv,t5=btv,t6=btv,t7=btv;
        float4 E0,E1,H0,H1,F0,F1,Q0,Q1, e0,e1,g0,g1,f0,f1,q0,q1;
        float4 wxh = *(const float4*)&TXh[(size_t)(b0 * 512 + c) * 4];
        float4 whh = *(const float4*)&THh[(size_t)(b0 * 512 + c) * 4];
        float4 wxt = *(const float4*)&TXt[(size_t)(b0 * 512 + c) * 4];
        float4 wht = *(const float4*)&THt[(size_t)(b0 * 512 + c) * 4];
        RDB(E0,E1,H0,H1,F0,F1,Q0,Q1, b0 * 4);
        for (int k4 = 0; k4 < 32; ++k4) {
          const int kk = (k4 + b0) & 31, kkn = (k4 + 1 + b0) & 31;
          float4 wxhn = *(const float4*)&TXh[(size_t)(kkn * 512 + c) * 4];
          float4 whhn = *(const float4*)&THh[(size_t)(kkn * 512 + c) * 4];
          float4 wxtn = *(const float4*)&TXt[(size_t)(kkn * 512 + c) * 4];
          float4 whtn = *(const float4*)&THt[(size_t)(kkn * 512 + c) * 4];
          const int d4 = kk * 4;
          RDB(e0,e1,g0,g1,f0,f1,q0,q1, d4 + 1);
          FMAB(wxh.x, whh.x, wxt.x, wht.x, E0,E1,H0,H1,F0,F1,Q0,Q1);
          RDB(E0,E1,H0,H1,F0,F1,Q0,Q1, d4 + 2);
          FMAB(wxh.y, whh.y, wxt.y, wht.y, e0,e1,g0,g1,f0,f1,q0,q1);
          RDB(e0,e1,g0,g1,f0,f1,q0,q1, d4 + 3);
          FMAB(wxh.z, whh.z, wxt.z, wht.z, E0,E1,H0,H1,F0,F1,Q0,Q1);
          RDB(E0,E1,H0,H1,F0,F1,Q0,Q1, kkn * 4);
          FMAB(wxh.w, whh.w, wxt.w, wht.w, e0,e1,g0,g1,f0,f1,q0,q1);
          wxh = wxhn; whh = whhn; wxt = wxtn; wht = whtn;
        }
        __syncthreads();            // A-region dead -> Z overlay
        *(float4*)&S_[O_ZH + c * 8]     = make_float4(h0, h1, h2, h3);
        *(float4*)&S_[O_ZH + c * 8 + 4] = make_float4(h4, h5, h6, h7);
        *(float4*)&S_[O_ZT + c * 8]     = make_float4(t0, t1, t2, t3);
        *(float4*)&S_[O_ZT + c * 8 + 4] = make_float4(t4, t5, t6, t7);
      }
      __syncthreads();

      // -------- Phase C: gates, c/h update, scatter state, rt update
      {
        const int side = tid >> 8, sub = (tid >> 7) & 1, e2 = tid & 127;
        const int zo = side ? O_ZT : O_ZH;
        const int co = side ? O_CAT : O_CAH;
        const int no = side ? O_ET : O_EH;
        float* ctab = side ? p.cell_tail : p.cell_head;
        float* htab = side ? p.hidden_tail : p.hidden_head;
        for (int q = 0; q < 4; ++q) {
          int g = sub + 2 * q;
          if (g >= ng) continue;
          float iv = sigmoidf(S_[zo + e2 * 8 + g]);
          float fv = sigmoidf(S_[zo + (128 + e2) * 8 + g]);
          float ov = sigmoidf(S_[zo + (256 + e2) * 8 + g]);
          float gv = tanhf(S_[zo + (384 + e2) * 8 + g]);
          float cadj = S_[co + e2 * 8 + g];
          float cn = fv * cadj + iv * gv;
          float hn = ov * tanhf(cn);
          S_[no + e2 * 8 + g] = hn;
          int node = side ? tIdx[g] : hIdx[g];
          ctab[(size_t)node * DD + e2] = cn;
          htab[(size_t)node * DD + e2] = hn;
        }
        if (tid < 2 * G) {
          int g = tid & (G - 1);
          if (g < ng) p.rt[(tid >= G) ? tIdx[g] : hIdx[g]] = tmv[g];
        }
      }
      __syncthreads();

      // -------- Phase D: combiner, rep scatter (tail wins on h==t)
      {
        const int role = tid >> 7, e = tid & 127;
        if (role <= 1) {
          const int xo = role ? O_HHT : O_EH;     // @ Wc1
          const int yo = role ? O_ET : O_HTH;     // @ Wc2
          const float* W1 = p.Wt[6];
          const float* W2 = p.Wt[7];
          float a0=0.f,a1=0.f,a2=0.f,a3=0.f,a4=0.f,a5=0.f,a6=0.f,a7=0.f;
          float4 c0,c1,c2,c3,n0,n1,n2,n3;
          float4 w1v = *(const float4*)&W1[(b0 * 128 + e) * 4];
          float4 w2v = *(const float4*)&W2[(b0 * 128 + e) * 4];
          RD4(c0,c1,c2,c3, xo, yo, b0 * 4);
#pragma unroll 2
          for (int k4 = 0; k4 < 32; ++k4) {
            const int kk = (k4 + b0) & 31, kkn = (k4 + 1 + b0) & 31;
            float4 w1n = *(const float4*)&W1[(kkn * 128 + e) * 4];
            float4 w2n = *(const float4*)&W2[(kkn * 128 + e) * 4];
            const int d4 = kk * 4;
            RD4(n0,n1,n2,n3, xo, yo, d4 + 1); FMA8(w1v.x, w2v.x, c0,c1,c2,c3);
            RD4(c0,c1,c2,c3, xo, yo, d4 + 2); FMA8(w1v.y, w2v.y, n0,n1,n2,n3);
            RD4(n0,n1,n2,n3, xo, yo, d4 + 3); FMA8(w1v.z, w2v.z, c0,c1,c2,c3);
            RD4(c0,c1,c2,c3, xo, yo, kkn * 4); FMA8(w1v.w, w2v.w, n0,n1,n2,n3);
            w1v = w1n; w2v = w2n;
          }
          float r[8] = {a0, a1, a2, a3, a4, a5, a6, a7};
          if (role == 0) {
#pragma unroll
            for (int g = 0; g < 8; ++g)
              if (g < ng && hIdx[g] != tIdx[g])
                p.node_rep[(size_t)hIdx[g] * DD + e] = tanhf(r[g]);
          } else {
#pragma unroll
            for (int g = 0; g < 8; ++g)
              if (g < ng)
                p.node_rep[(size_t)tIdx[g] * DD + e] = tanhf(r[g]);
          }
        }
      }
    }
    __threadfence();
    grid.sync();
  }
}

// ---------------------------------------------------------------------------
extern "C" void kernel_launch(void* const* d_in, const int* in_sizes, int n_in,
                              void* d_out, int out_size, void* d_ws, size_t ws_size,
                              hipStream_t stream) {
  const int* heads = (const int*)d_in[0];
  const int* tails = (const int*)d_in[1];
  const float* times = (const float*)d_in[2];
  float* node_rep    = (float*)d_in[3];
  float* cell_head   = (float*)d_in[4];
  float* hidden_head = (float*)d_in[5];
  float* cell_tail   = (float*)d_in[6];
  float* hidden_tail = (float*)d_in[7];

  const int S = in_sizes[0];
  const int N = in_sizes[3] / DD;

  char* ws = (char*)d_ws;
  size_t off = 0;
  float* rt = (float*)ws;
  off = (((size_t)N * 4) + 511) & ~(size_t)511;
  int* order     = (int*)(ws + off); off += (size_t)SMAX * 4;
  int* level_off = (int*)(ws + off); off += (size_t)(SMAX + 1) * 4;
  int* n_levels  = (int*)(ws + off); off += 64 * 4;
  int* ph        = (int*)(ws + off); off += (size_t)SMAX * 4;
  int* pt        = (int*)(ws + off); off += (size_t)SMAX * 4;
  off = (off + 255) & ~(size_t)255;

  PParams p;
  p.heads = heads; p.tails = tails; p.times = times;
  p.node_rep = node_rep; p.cell_head = cell_head; p.hidden_head = hidden_head;
  p.cell_tail = cell_tail; p.hidden_tail = hidden_tail;
  p.beh = (const float*)d_in[10]; p.bet = (const float*)d_in[13];
  p.bh  = (const float*)d_in[16]; p.bt  = (const float*)d_in[21];
  p.bdh = (const float*)d_in[18]; p.bdt = (const float*)d_in[23];
  p.Wsrc[0] = (const float*)d_in[8];   // Weh1
  p.Wsrc[1] = (const float*)d_in[9];   // Weh2
  p.Wsrc[2] = (const float*)d_in[11];  // Wet1
  p.Wsrc[3] = (const float*)d_in[12];  // Wet2
  p.Wsrc[4] = (const float*)d_in[17];  // Wdh
  p.Wsrc[5] = (const float*)d_in[22];  // Wdt
  p.Wsrc[6] = (const float*)d_in[24];  // Wc1
  p.Wsrc[7] = (const float*)d_in[25];  // Wc2
  p.Wsrc[8] = (const float*)d_in[14];  // Wxh
  p.Wsrc[9] = (const float*)d_in[15];  // Whh
  p.Wsrc[10] = (const float*)d_in[19]; // Wxt
  p.Wsrc[11] = (const float*)d_in[20]; // Wht

  for (int m = 0; m < 12; ++m) {
    size_t n = (m < 8) ? 16384 : 65536;
    p.Wt[m] = (float*)(ws + off); off += n * 4;
  }

  p.out = (float*)d_out; p.rt = rt;
  p.order = order; p.level_off = level_off; p.n_levels = n_levels;
  p.ph = ph; p.pt = pt;
  p.S = S;

  hipMemsetAsync(rt, 0, (size_t)N * 4, stream);

  void* args[] = { (void*)&p };

  int dev = 0; hipGetDevice(&dev);
  int nCU = 0;
  hipDeviceGetAttribute(&nCU, hipDeviceAttributeMultiprocessorCount, dev);
  if (nCU <= 0) nCU = 256;
  int maxBlkPerCU = 0;
  if (hipOccupancyMaxActiveBlocksPerMultiprocessor(&maxBlkPerCU, process_kernel, TPB, 0)
      != hipSuccess || maxBlkPerCU < 1)
    maxBlkPerCU = 1;
  long long cap = (long long)nCU * (long long)maxBlkPerCU;
  int grid = (int)(cap < NBLK_MAX ? cap : NBLK_MAX);
  if (grid < 1) grid = nCU;

  hipError_t err = hipLaunchCooperativeKernel(process_kernel, dim3(grid), dim3(TPB),
                                              args, 0, stream);
  if (err != hipSuccess && grid > 128) {
    err = hipLaunchCooperativeKernel(process_kernel, dim3(128), dim3(TPB), args, 0, stream);
    grid = 128;
  }
  if (err != hipSuccess && grid > 64) {
    err = hipLaunchCooperativeKernel(process_kernel, dim3(64), dim3(TPB), args, 0, stream);
  }
}